// Round 11
// baseline (238.027 us; speedup 1.0000x reference)
//
#include <hip/hip_runtime.h>
#include <math.h>

#define HH 224
#define WW 224
#define TH 32
#define TW 32
#define TILES_X 7
#define HALO 36
#define BOXH 56
#define BOXW 57          // LDS stride for the source box (+1 high-end pad)
#define WTS  40          // 160B rows -> float4-aligned
#define TMPS 40

typedef float nt_float4 __attribute__((ext_vector_type(4)));  // native vec for nontemporal builtins

struct __align__(16) ImgParams {
    float ca, sa, ay, by;   // rotation + y-affine (sy = ay*yr + by)
    float ax, bx, w0, w1;   // x-affine (flip folded in) + blur taps
    float w2, w3, w4, pad;
};

// ---------------- amap: channel -> augment index (or -1) ----------------
__global__ void amap_kernel(const int* __restrict__ channel_idx, int n_aug, int c,
                            int* __restrict__ amap) {
    int t = threadIdx.x;
    for (int i = t; i < c; i += blockDim.x) amap[i] = -1;
    __syncthreads();
    for (int i = t; i < n_aug; i += blockDim.x) amap[channel_idx[i]] = i;
}

// ---------------- per-image params: all transcendentals, once per image ----------------
__global__ void params_kernel(const float* __restrict__ aug_u,
                              ImgParams* __restrict__ params, int N) {
    int n = blockIdx.x * blockDim.x + threadIdx.x;
    if (n >= N) return;
    const float* u = aug_u + (size_t)n * 7;
    const float u0 = u[0], u1 = u[1], u2 = u[2], u3 = u[3], u4 = u[4], u5 = u[5], u6 = u[6];

    const float area  = (float)(HH * WW) * (0.8f + 0.2f * u0);
    const float lo    = logf(0.75f);
    const float hi    = logf(4.0f / 3.0f);
    const float ratio = expf(lo + (hi - lo) * u1);
    float wc = sqrtf(area * ratio);
    float hc = sqrtf(area / ratio);
    wc = fminf(fmaxf(wc, 1.0f), (float)WW);
    hc = fminf(fmaxf(hc, 1.0f), (float)HH);
    const float fi    = u2 * ((float)HH - hc);
    const float fj    = u3 * ((float)WW - wc);
    const bool  flip  = u4 < 0.5f;
    const float angle = u5 * 3.14159274101257324f;
    const float sigma = 0.1f + 1.9f * u6;

    ImgParams p;
    p.ca = cosf(angle);
    p.sa = sinf(angle);
    const float syk = hc / (float)HH;
    const float sxk = wc / (float)WW;
    p.ay = syk;
    p.by = 0.5f * syk - 0.5f + fi;
    if (flip) {
        p.ax = -sxk;
        p.bx = ((float)WW - 0.5f) * sxk - 0.5f + fj;
    } else {
        p.ax = sxk;
        p.bx = 0.5f * sxk - 0.5f + fj;
    }
    float wk[5], wsum = 0.f;
    const float inv2s2 = 1.0f / (2.0f * sigma * sigma);
    #pragma unroll
    for (int k = 0; k < 5; ++k) {
        float d = (float)k - 2.0f;
        wk[k] = expf(-(d * d) * inv2s2);
        wsum += wk[k];
    }
    float inv = 1.0f / wsum;
    p.w0 = wk[0] * inv; p.w1 = wk[1] * inv; p.w2 = wk[2] * inv;
    p.w3 = wk[3] * inv; p.w4 = wk[4] * inv;
    p.pad = 0.f;
    params[n] = p;
}

// ---------------- fused: copy (non-aug) OR warp+blur+noise (aug) ----------------
__global__ __launch_bounds__(256) void fused_kernel(
        const float* __restrict__ M, const int* __restrict__ amap,
        const ImgParams* __restrict__ params, const float* __restrict__ noise,
        float* __restrict__ out, int c, int n_aug, int swz) {
    // ---- XCD-locality decode: all 49 tiles of a unit share one XCD residue ----
    int id = blockIdx.x;
    int tile, u;
    if (swz) {
        int low  = id & 7;
        int rest = id >> 3;
        int uh   = rest / 49;
        tile     = rest - uh * 49;
        u        = (uh << 3) | low;
    } else {
        u    = id / 49;
        tile = id - u * 49;
    }
    const int bi = u / c;
    const int ch = u - bi * c;

    const int tid  = threadIdx.x;
    const int a    = amap[ch];
    const size_t chanoff = ((size_t)bi * c + ch) * (HH * WW);

    if (a < 0) {
        // -------- copy path: 49 blocks x 256 float4 == 224*224 floats --------
        const nt_float4* __restrict__ src = (const nt_float4*)(M + chanoff);
        nt_float4* __restrict__ dst = (nt_float4*)(out + chanoff);
        int off = tile * 256 + tid;
        __builtin_nontemporal_store(__builtin_nontemporal_load(&src[off]), &dst[off]);
        return;
    }

    // -------- augment path --------
    const int n  = bi * n_aug + a;
    const int ty = tile / TILES_X;
    const int y0 = ty * TH;
    const int x0 = (tile - ty * TILES_X) * TW;

    const ImgParams P = params[n];          // uniform -> scalar loads
    const float* __restrict__ img = M + chanoff;

    __shared__ __align__(16) float Box[BOXH * BOXW];   // 12.8 KB; aliased as Tmp later
    __shared__ __align__(16) float Wt[HALO][WTS];      // 5.8 KB

    const float cc = 111.5f;

    // ---- bounding box of source coords (block-uniform scalar math) ----
    const int ry_lo = max(y0 - 2, 0),  ry_hi = min(y0 + 33, HH - 1);
    const int rx_lo = max(x0 - 2, 0),  rx_hi = min(x0 + 33, WW - 1);
    const float dyl = (float)ry_lo - cc, dyh = (float)ry_hi - cc;
    const float dxl = (float)rx_lo - cc, dxh = (float)rx_hi - cc;
    float yr_min = cc + fminf(P.ca * dyl, P.ca * dyh) + P.sa * dxl;
    float yr_max = cc + fmaxf(P.ca * dyl, P.ca * dyh) + P.sa * dxh;
    float xr_min = cc + fminf(P.ca * dxl, P.ca * dxh) - P.sa * dyh;
    float xr_max = cc + fmaxf(P.ca * dxl, P.ca * dxh) - P.sa * dyl;
    yr_min = fmaxf(yr_min, -0.5f); yr_max = fminf(yr_max, (float)HH - 0.5f);
    xr_min = fmaxf(xr_min, -0.5f); xr_max = fminf(xr_max, (float)WW - 0.5f);
    const float sy_min = P.ay * yr_min + P.by, sy_max = P.ay * yr_max + P.by;
    const float sx_a = P.ax * xr_min + P.bx,  sx_b = P.ax * xr_max + P.bx;
    const float sx_min = fminf(sx_a, sx_b), sx_max = fmaxf(sx_a, sx_b);
    const int by0 = min(max((int)floorf(sy_min), 0), HH - 1);
    const int by1 = min(max((int)floorf(sy_max) + 1, 0), HH - 1);
    const int bx0 = min(max((int)floorf(sx_min), 0), WW - 1);
    const int bx1 = min(max((int)floorf(sx_max) + 1, 0), WW - 1);
    const int bh = max(by1 - by0 + 1, 0);   // <= 52 rows of real data
    const int bw = bx1 - bx0 + 1;           // <= 52 cols

    // ---- coalesced load of the box into LDS, +1 high-end pad (clamped src) ----
    // Reference clamps yi FIRST, then neighbor is yi+1 (re-clamped). So per-sample
    // index must clamp low side; pad row/col only absorbs the +1 neighbor at 223.
    // (round-10 lesson: clamp-pad must match the reference's clamp ORDER.)
    {
        const int q = tid & 63;
        if (q <= bw) {
            int scol = min(bx0 + q, WW - 1);
            for (int r = tid >> 6; r <= bh; r += 4) {
                int srow = min(by0 + r, HH - 1);
                Box[r * BOXW + q] = img[srow * WW + scol];
            }
        }
    }
    __syncthreads();

    // ---- warp into halo tile: thread = (row, 6 consecutive x) ----
    // NOTE: per-sample math uses the EXACT reference association
    // (yr = ca*dy + sa*dx + cc, explicit range check) — feeding the
    // discontinuous inb/zero-fill decision; do NOT re-associate (round-6 fail).
    if (tid < 216) {
        const int hy  = tid / 6;
        const int g   = tid - hy * 6;
        const int hx0 = g * 6;
        int vy = y0 + hy - 2;
        int ayv = abs(vy);
        int ry = min(ayv, 2 * (HH - 1) - ayv);   // reflect
        const float dy = (float)ry - cc;
        const int kbase = -(by0 * BOXW + bx0);
        float acc[6];
        #pragma unroll
        for (int j = 0; j < 6; ++j) {
            int vx = x0 + hx0 + j - 2;
            int axv = abs(vx);
            int rx = min(axv, 2 * (WW - 1) - axv);
            float dx = (float)rx - cc;
            float yr = P.ca * dy + P.sa * dx + cc;
            float xr = P.ca * dx - P.sa * dy + cc;
            float val = 0.f;
            if (yr >= -0.5f && yr <= (float)HH - 0.5f &&
                xr >= -0.5f && xr <= (float)WW - 0.5f) {
                float sy = P.ay * yr + P.by;
                float sx = P.ax * xr + P.bx;
                float fy = floorf(sy), fx = floorf(sx);
                float wy = sy - fy, wx = sx - fx;
                int yi = min(max((int)fy, 0), HH - 1);   // clamp FIRST (ref order)
                int xi = min(max((int)fx, 0), WW - 1);
                int k = yi * BOXW + xi + kbase;
                float v00 = Box[k],        v01 = Box[k + 1];
                float v10 = Box[k + BOXW], v11 = Box[k + BOXW + 1];
                float top = v00 + (v01 - v00) * wx;
                float bot = v10 + (v11 - v10) * wx;
                val = top + (bot - top) * wy;
            }
            acc[j] = val;
        }
        float2* wrow = (float2*)&Wt[hy][hx0];
        wrow[0] = make_float2(acc[0], acc[1]);
        wrow[1] = make_float2(acc[2], acc[3]);
        wrow[2] = make_float2(acc[4], acc[5]);
    }
    __syncthreads();

    // ---- vertical blur: 32 rows x 9 col-quads, float4 ----
    float* __restrict__ Tmp = Box;   // alias; safe after barrier
    for (int u2 = tid; u2 < TH * 9; u2 += 256) {
        int vy = u2 / 9, q = u2 - vy * 9;
        int x = 4 * q;
        float4 a0 = *(const float4*)&Wt[vy][x];
        float4 a1 = *(const float4*)&Wt[vy + 1][x];
        float4 a2 = *(const float4*)&Wt[vy + 2][x];
        float4 a3 = *(const float4*)&Wt[vy + 3][x];
        float4 a4 = *(const float4*)&Wt[vy + 4][x];
        float4 s;
        s.x = P.w0 * a0.x + P.w1 * a1.x + P.w2 * a2.x + P.w3 * a3.x + P.w4 * a4.x;
        s.y = P.w0 * a0.y + P.w1 * a1.y + P.w2 * a2.y + P.w3 * a3.y + P.w4 * a4.y;
        s.z = P.w0 * a0.z + P.w1 * a1.z + P.w2 * a2.z + P.w3 * a3.z + P.w4 * a4.z;
        s.w = P.w0 * a0.w + P.w1 * a1.w + P.w2 * a2.w + P.w3 * a3.w + P.w4 * a4.w;
        *(float4*)&Tmp[vy * TMPS + x] = s;
    }
    __syncthreads();

    // ---- horizontal blur + noise + write, 4 px/thread, float4 ----
    const float* __restrict__ npz = noise + (size_t)n * (HH * WW);
    float* __restrict__ op = out + chanoff;
    {
        int yy = tid >> 3, p = tid & 7;
        int x = 4 * p;
        const float* t = Tmp + yy * TMPS + x;
        float4 ta = *(const float4*)(t);       // t0..t3
        float4 tb = *(const float4*)(t + 4);   // t4..t7
        float s0 = P.w0 * ta.x + P.w1 * ta.y + P.w2 * ta.z + P.w3 * ta.w + P.w4 * tb.x;
        float s1 = P.w0 * ta.y + P.w1 * ta.z + P.w2 * ta.w + P.w3 * tb.x + P.w4 * tb.y;
        float s2 = P.w0 * ta.z + P.w1 * ta.w + P.w2 * tb.x + P.w3 * tb.y + P.w4 * tb.z;
        float s3 = P.w0 * ta.w + P.w1 * tb.x + P.w2 * tb.y + P.w3 * tb.z + P.w4 * tb.w;
        size_t o = (size_t)(y0 + yy) * WW + (x0 + x);
        nt_float4 nz = __builtin_nontemporal_load((const nt_float4*)(npz + o));
        nt_float4 r;
        r.x = s0 + 0.05f * nz.x; r.y = s1 + 0.05f * nz.y;
        r.z = s2 + 0.05f * nz.z; r.w = s3 + 0.05f * nz.w;
        __builtin_nontemporal_store(r, (nt_float4*)(op + o));
    }
}

extern "C" void kernel_launch(void* const* d_in, const int* in_sizes, int n_in,
                              void* d_out, int out_size, void* d_ws, size_t ws_size,
                              hipStream_t stream) {
    const float* M           = (const float*)d_in[0];
    const int*   channel_idx = (const int*)d_in[1];
    const float* aug_u       = (const float*)d_in[2];
    const float* noise       = (const float*)d_in[3];
    float* out = (float*)d_out;

    const int n_aug = in_sizes[1];
    const int b     = in_sizes[2] / (n_aug * 7);
    const int c     = in_sizes[0] / (b * HH * WW);
    const int N     = b * n_aug;

    int* amap = (int*)d_ws;
    ImgParams* params = (ImgParams*)((char*)d_ws + 4096);

    amap_kernel<<<1, 256, 0, stream>>>(channel_idx, n_aug, c, amap);
    params_kernel<<<(N + 255) / 256, 256, 0, stream>>>(aug_u, params, N);

    const int units = b * c;
    const int swz   = (units % 8 == 0) ? 1 : 0;
    fused_kernel<<<49 * units, 256, 0, stream>>>(M, amap, params, noise, out,
                                                 c, n_aug, swz);
}

// Round 12
// 222.539 us; speedup vs baseline: 1.0696x; 1.0696x over previous
//
#include <hip/hip_runtime.h>
#include <math.h>

#define HH 224
#define WW 224
#define TH 32
#define TW 32
#define TILES_X 7
#define HALO 36
#define BOXH 56
#define BOXW 57          // LDS stride for the source box (+1 high-end pad)
#define WTS  40          // 160B rows -> float4-aligned
#define TMPS 40

typedef float nt_float4 __attribute__((ext_vector_type(4)));  // native vec for nontemporal builtins

struct __align__(16) ImgParams {
    float ca, sa, ay, by;   // rotation + y-affine (sy = ay*yr + by)
    float ax, bx, w0, w1;   // x-affine (flip folded in) + blur taps
    float w2, w3, w4, pad;
};

// ---------------- copy_list: compacted non-augmented channels ----------------
__global__ void copylist_kernel(const int* __restrict__ channel_idx, int n_aug, int c,
                                int* __restrict__ copy_list, int* __restrict__ mark) {
    int t = threadIdx.x;
    for (int i = t; i < c; i += 256) mark[i] = 0;
    __syncthreads();
    for (int i = t; i < n_aug; i += 256) mark[channel_idx[i]] = 1;
    __syncthreads();
    __shared__ int cnt;
    if (t == 0) cnt = 0;
    __syncthreads();
    for (int i = t; i < c; i += 256) {
        if (!mark[i]) {
            int p = atomicAdd(&cnt, 1);
            copy_list[p] = i;
        }
    }
}

// ---------------- per-image params: all transcendentals, once per image ----------------
__global__ void params_kernel(const float* __restrict__ aug_u,
                              ImgParams* __restrict__ params, int N) {
    int n = blockIdx.x * blockDim.x + threadIdx.x;
    if (n >= N) return;
    const float* u = aug_u + (size_t)n * 7;
    const float u0 = u[0], u1 = u[1], u2 = u[2], u3 = u[3], u4 = u[4], u5 = u[5], u6 = u[6];

    const float area  = (float)(HH * WW) * (0.8f + 0.2f * u0);
    const float lo    = logf(0.75f);
    const float hi    = logf(4.0f / 3.0f);
    const float ratio = expf(lo + (hi - lo) * u1);
    float wc = sqrtf(area * ratio);
    float hc = sqrtf(area / ratio);
    wc = fminf(fmaxf(wc, 1.0f), (float)WW);
    hc = fminf(fmaxf(hc, 1.0f), (float)HH);
    const float fi    = u2 * ((float)HH - hc);
    const float fj    = u3 * ((float)WW - wc);
    const bool  flip  = u4 < 0.5f;
    const float angle = u5 * 3.14159274101257324f;
    const float sigma = 0.1f + 1.9f * u6;

    ImgParams p;
    p.ca = cosf(angle);
    p.sa = sinf(angle);
    const float syk = hc / (float)HH;
    const float sxk = wc / (float)WW;
    p.ay = syk;
    p.by = 0.5f * syk - 0.5f + fi;
    if (flip) {
        p.ax = -sxk;
        p.bx = ((float)WW - 0.5f) * sxk - 0.5f + fj;
    } else {
        p.ax = sxk;
        p.bx = 0.5f * sxk - 0.5f + fj;
    }
    float wk[5], wsum = 0.f;
    const float inv2s2 = 1.0f / (2.0f * sigma * sigma);
    #pragma unroll
    for (int k = 0; k < 5; ++k) {
        float d = (float)k - 2.0f;
        wk[k] = expf(-(d * d) * inv2s2);
        wsum += wk[k];
    }
    float inv = 1.0f / wsum;
    p.w0 = wk[0] * inv; p.w1 = wk[1] * inv; p.w2 = wk[2] * inv;
    p.w3 = wk[3] * inv; p.w4 = wk[4] * inv;
    p.pad = 0.f;
    params[n] = p;
}

__device__ __forceinline__ void swz_decode(int id, int swz, int& unit, int& tile) {
    if (swz) {
        int low  = id & 7;
        int rest = id >> 3;
        int uh   = rest / 49;
        tile     = rest - uh * 49;
        unit     = (uh << 3) | low;
    } else {
        unit = id / 49;
        tile = id - unit * 49;
    }
}

// ---------------- fused: augment section then copy section ----------------
__global__ __launch_bounds__(256) void fused_kernel(
        const float* __restrict__ M, const int* __restrict__ channel_idx,
        const int* __restrict__ copy_list, const ImgParams* __restrict__ params,
        const float* __restrict__ noise, float* __restrict__ out,
        int c, int n_aug, int n_copy, int aug_blocks, int swz) {
    const int tid = threadIdx.x;
    int id = blockIdx.x;

    if (id >= aug_blocks) {
        // -------- copy section: balanced across XCDs by construction --------
        int unit, tile;
        swz_decode(id - aug_blocks, swz, unit, tile);
        const int bi = unit / n_copy;
        const int ci = unit - bi * n_copy;
        const int ch = copy_list[ci];
        const size_t chanoff = ((size_t)bi * c + ch) * (HH * WW);
        const nt_float4* __restrict__ src = (const nt_float4*)(M + chanoff);
        nt_float4* __restrict__ dst = (nt_float4*)(out + chanoff);
        int off = tile * 256 + tid;
        __builtin_nontemporal_store(__builtin_nontemporal_load(&src[off]), &dst[off]);
        return;
    }

    // -------- augment section --------
    int unit, tile;
    swz_decode(id, swz, unit, tile);
    const int bi = unit / n_aug;
    const int a  = unit - bi * n_aug;
    const int ch = channel_idx[a];
    const int n  = unit;                    // bi * n_aug + a
    const size_t chanoff = ((size_t)bi * c + ch) * (HH * WW);

    const int ty = tile / TILES_X;
    const int y0 = ty * TH;
    const int x0 = (tile - ty * TILES_X) * TW;

    const ImgParams P = params[n];          // uniform -> scalar loads
    const float* __restrict__ img = M + chanoff;

    __shared__ __align__(16) float Box[BOXH * BOXW];   // 12.8 KB; aliased as Tmp later
    __shared__ __align__(16) float Wt[HALO][WTS];      // 5.8 KB

    const float cc = 111.5f;

    // ---- bounding box of source coords (block-uniform scalar math) ----
    const int ry_lo = max(y0 - 2, 0),  ry_hi = min(y0 + 33, HH - 1);
    const int rx_lo = max(x0 - 2, 0),  rx_hi = min(x0 + 33, WW - 1);
    const float dyl = (float)ry_lo - cc, dyh = (float)ry_hi - cc;
    const float dxl = (float)rx_lo - cc, dxh = (float)rx_hi - cc;
    float yr_min = cc + fminf(P.ca * dyl, P.ca * dyh) + P.sa * dxl;
    float yr_max = cc + fmaxf(P.ca * dyl, P.ca * dyh) + P.sa * dxh;
    float xr_min = cc + fminf(P.ca * dxl, P.ca * dxh) - P.sa * dyh;
    float xr_max = cc + fmaxf(P.ca * dxl, P.ca * dxh) - P.sa * dyl;
    yr_min = fmaxf(yr_min, -0.5f); yr_max = fminf(yr_max, (float)HH - 0.5f);
    xr_min = fmaxf(xr_min, -0.5f); xr_max = fminf(xr_max, (float)WW - 0.5f);
    const float sy_min = P.ay * yr_min + P.by, sy_max = P.ay * yr_max + P.by;
    const float sx_a = P.ax * xr_min + P.bx,  sx_b = P.ax * xr_max + P.bx;
    const float sx_min = fminf(sx_a, sx_b), sx_max = fmaxf(sx_a, sx_b);
    const int by0 = min(max((int)floorf(sy_min), 0), HH - 1);
    const int by1 = min(max((int)floorf(sy_max) + 1, 0), HH - 1);
    const int bx0 = min(max((int)floorf(sx_min), 0), WW - 1);
    const int bx1 = min(max((int)floorf(sx_max) + 1, 0), WW - 1);
    const int bh = max(by1 - by0 + 1, 0);   // <= 52 rows of real data
    const int bw = bx1 - bx0 + 1;           // <= 52 cols

    // ---- coalesced load of the box into LDS, +1 high-end pad (clamped src) ----
    // Reference clamps yi FIRST, then neighbor is yi+1 (re-clamped): per-sample
    // clamp on the low side stays; pad only absorbs the +1 neighbor at 223.
    {
        const int q = tid & 63;
        if (q <= bw) {
            int scol = min(bx0 + q, WW - 1);
            for (int r = tid >> 6; r <= bh; r += 4) {
                int srow = min(by0 + r, HH - 1);
                Box[r * BOXW + q] = img[srow * WW + scol];
            }
        }
    }
    __syncthreads();

    // ---- warp into halo tile: thread = (row, 6 consecutive x) ----
    // NOTE: per-sample math uses the EXACT reference association
    // (yr = ca*dy + sa*dx + cc, explicit range check) — feeding the
    // discontinuous inb/zero-fill decision; do NOT re-associate (round-6 fail).
    if (tid < 216) {
        const int hy  = tid / 6;
        const int g   = tid - hy * 6;
        const int hx0 = g * 6;
        int vy = y0 + hy - 2;
        int ayv = abs(vy);
        int ry = min(ayv, 2 * (HH - 1) - ayv);   // reflect
        const float dy = (float)ry - cc;
        const int kbase = -(by0 * BOXW + bx0);
        float acc[6];
        #pragma unroll
        for (int j = 0; j < 6; ++j) {
            int vx = x0 + hx0 + j - 2;
            int axv = abs(vx);
            int rx = min(axv, 2 * (WW - 1) - axv);
            float dx = (float)rx - cc;
            float yr = P.ca * dy + P.sa * dx + cc;
            float xr = P.ca * dx - P.sa * dy + cc;
            float val = 0.f;
            if (yr >= -0.5f && yr <= (float)HH - 0.5f &&
                xr >= -0.5f && xr <= (float)WW - 0.5f) {
                float sy = P.ay * yr + P.by;
                float sx = P.ax * xr + P.bx;
                float fy = floorf(sy), fx = floorf(sx);
                float wy = sy - fy, wx = sx - fx;
                int yi = min(max((int)fy, 0), HH - 1);   // clamp FIRST (ref order)
                int xi = min(max((int)fx, 0), WW - 1);
                int k = yi * BOXW + xi + kbase;
                float v00 = Box[k],        v01 = Box[k + 1];
                float v10 = Box[k + BOXW], v11 = Box[k + BOXW + 1];
                float top = v00 + (v01 - v00) * wx;
                float bot = v10 + (v11 - v10) * wx;
                val = top + (bot - top) * wy;
            }
            acc[j] = val;
        }
        float2* wrow = (float2*)&Wt[hy][hx0];
        wrow[0] = make_float2(acc[0], acc[1]);
        wrow[1] = make_float2(acc[2], acc[3]);
        wrow[2] = make_float2(acc[4], acc[5]);
    }
    __syncthreads();

    // ---- vertical blur: 32 rows x 9 col-quads, float4 ----
    float* __restrict__ Tmp = Box;   // alias; safe after barrier
    for (int u2 = tid; u2 < TH * 9; u2 += 256) {
        int vy = u2 / 9, q = u2 - vy * 9;
        int x = 4 * q;
        float4 a0 = *(const float4*)&Wt[vy][x];
        float4 a1 = *(const float4*)&Wt[vy + 1][x];
        float4 a2 = *(const float4*)&Wt[vy + 2][x];
        float4 a3 = *(const float4*)&Wt[vy + 3][x];
        float4 a4 = *(const float4*)&Wt[vy + 4][x];
        float4 s;
        s.x = P.w0 * a0.x + P.w1 * a1.x + P.w2 * a2.x + P.w3 * a3.x + P.w4 * a4.x;
        s.y = P.w0 * a0.y + P.w1 * a1.y + P.w2 * a2.y + P.w3 * a3.y + P.w4 * a4.y;
        s.z = P.w0 * a0.z + P.w1 * a1.z + P.w2 * a2.z + P.w3 * a3.z + P.w4 * a4.z;
        s.w = P.w0 * a0.w + P.w1 * a1.w + P.w2 * a2.w + P.w3 * a3.w + P.w4 * a4.w;
        *(float4*)&Tmp[vy * TMPS + x] = s;
    }
    __syncthreads();

    // ---- horizontal blur + noise + write, 4 px/thread, float4 ----
    const float* __restrict__ npz = noise + (size_t)n * (HH * WW);
    float* __restrict__ op = out + chanoff;
    {
        int yy = tid >> 3, p = tid & 7;
        int x = 4 * p;
        const float* t = Tmp + yy * TMPS + x;
        float4 ta = *(const float4*)(t);       // t0..t3
        float4 tb = *(const float4*)(t + 4);   // t4..t7
        float s0 = P.w0 * ta.x + P.w1 * ta.y + P.w2 * ta.z + P.w3 * ta.w + P.w4 * tb.x;
        float s1 = P.w0 * ta.y + P.w1 * ta.z + P.w2 * ta.w + P.w3 * tb.x + P.w4 * tb.y;
        float s2 = P.w0 * ta.z + P.w1 * ta.w + P.w2 * tb.x + P.w3 * tb.y + P.w4 * tb.z;
        float s3 = P.w0 * ta.w + P.w1 * tb.x + P.w2 * tb.y + P.w3 * tb.z + P.w4 * tb.w;
        size_t o = (size_t)(y0 + yy) * WW + (x0 + x);
        nt_float4 nz = __builtin_nontemporal_load((const nt_float4*)(npz + o));
        nt_float4 r;
        r.x = s0 + 0.05f * nz.x; r.y = s1 + 0.05f * nz.y;
        r.z = s2 + 0.05f * nz.z; r.w = s3 + 0.05f * nz.w;
        __builtin_nontemporal_store(r, (nt_float4*)(op + o));
    }
}

extern "C" void kernel_launch(void* const* d_in, const int* in_sizes, int n_in,
                              void* d_out, int out_size, void* d_ws, size_t ws_size,
                              hipStream_t stream) {
    const float* M           = (const float*)d_in[0];
    const int*   channel_idx = (const int*)d_in[1];
    const float* aug_u       = (const float*)d_in[2];
    const float* noise       = (const float*)d_in[3];
    float* out = (float*)d_out;

    const int n_aug = in_sizes[1];
    const int b     = in_sizes[2] / (n_aug * 7);
    const int c     = in_sizes[0] / (b * HH * WW);
    const int N     = b * n_aug;
    const int n_copy = c - n_aug;

    int* copy_list = (int*)d_ws;
    int* mark      = (int*)((char*)d_ws + 2048);
    ImgParams* params = (ImgParams*)((char*)d_ws + 8192);

    copylist_kernel<<<1, 256, 0, stream>>>(channel_idx, n_aug, c, copy_list, mark);
    params_kernel<<<(N + 255) / 256, 256, 0, stream>>>(aug_u, params, N);

    const int aug_units  = b * n_aug;
    const int copy_units = b * n_copy;
    const int aug_blocks = 49 * aug_units;
    // swizzle only when both sections stay residue-aligned (aug_blocks % 8 == 0 too)
    const int swz = (aug_units % 8 == 0 && copy_units % 8 == 0) ? 1 : 0;
    fused_kernel<<<49 * (aug_units + copy_units), 256, 0, stream>>>(
        M, channel_idx, copy_list, params, noise, out,
        c, n_aug, n_copy, aug_blocks, swz);
}